// Round 4
// baseline (308.187 us; speedup 1.0000x reference)
//
#include <hip/hip_runtime.h>
#include <hip/hip_cooperative_groups.h>
#include <math.h>

namespace cg = cooperative_groups;

#define HH 512
#define WW 512
#define NPIX (HH*WW)
#define NB 32
#define NS 21           // 2*MS+1 shifts per axis
#define KWIN 492        // window size (H - 2*10)
#define MT28 28         // m-tiles (448 = 28*16, M=441 padded)
#define PARTSZ (MT28*32*16)   // 14336 floats per k-chunk

typedef __attribute__((ext_vector_type(8))) short short8;
typedef __attribute__((ext_vector_type(4))) float floatx4;

__device__ __forceinline__ unsigned short f2bf(float f) {
    unsigned u = __float_as_uint(f);
    unsigned r = (u + 0x7fffu + ((u >> 16) & 1u)) >> 16;
    return (unsigned short)r;
}

// ============================================================================
// ONE cooperative kernel, 256 blocks x 512 threads (1 block/CU co-resident).
// Phases separated by grid.sync():
//   P0: interior col partial sums (I1p/I2p, 8 oct-partials, NO atomics),
//       template partial sums (64 partials), tplv build (21 dv-shifted bf16).
//   P1: corr MFMA: each block = 2 k-chunks; B staged in LDS; 7 waves x 4 tiles.
//   P2: reduce part -> cc8 (per-oct, NO atomics) + stage2 denominator.
//   P3: argmax + log-parabola subpixel -> shifts.
//   P4: bilinear warp + transposed write.
// No hipMemsetAsync needed (all accumulators are fully-written partials).
// ============================================================================
__global__ __launch_bounds__(512) void motion_all(
    const float* __restrict__ fr, const float* __restrict__ tpl,
    unsigned short* __restrict__ tplv, float* __restrict__ part,
    float* __restrict__ cc8, float* __restrict__ I1p, float* __restrict__ I2p,
    double* __restrict__ tplS1p, double* __restrict__ tplS2p,
    double* __restrict__ sum1, float* __restrict__ denom,
    float* __restrict__ shifts, float* __restrict__ out)
{
    cg::grid_group grid = cg::this_grid();

    __shared__ unsigned short Bs[16384];       // 32 KB (P1)
    __shared__ float tile2[2][32][33];         // 8.4 KB (P4)
    __shared__ double wr1[NS][8], wr2[NS][8], wrT[8];
    __shared__ float  e1[NS][40], e2[NS][40];
    __shared__ double totals1[NS], totals2[NS];
    __shared__ double jb1[8], jb2[8];
    __shared__ double tS1s, tS2s;

    const int blk = blockIdx.x;
    const int t   = threadIdx.x;

    // ---------------- P0 -----------------------------------------------------
    {   // interior column sums: all 256 blocks = (frame b, row-oct)
        int b = blk >> 3, oct = blk & 7;
        const float* img = fr + (size_t)b * NPIX;
        int x = t;
        float s1 = 0.f, s2 = 0.f;
        int y0 = 20 + 59 * oct;                       // rows 20..491 = 8*59
        for (int y = y0; y < y0 + 59; ++y) {
            float v = img[(size_t)y * WW + x];
            s1 += v; s2 += v * v;
        }
        I1p[(size_t)blk * 512 + x] = s1;
        I2p[(size_t)blk * 512 + x] = s2;
    }
    {   // tplv build: rows r = dv*532+pr, 44 rows per block
        int rbeg = 44 * blk;
        int rend = min(rbeg + 44, NS * 532);
        int rp = t >> 8;                 // 0/1: two rows per iteration
        int xi = (t & 255) * 2;          // two pixels per thread
        for (int r2 = rbeg; r2 < rend; r2 += 2) {
            int r = r2 + rp;
            if (r < rend) {
                int dv = r / 532;
                int pr = r - 532 * dv;
                int sy = (pr + 502) & 511;            // (pr-10) mod 512
                const float* srow = tpl + (size_t)sy * WW;
                unsigned short* drow = tplv + (size_t)r * 512;
                int sx0 = (xi     - dv + 522) & 511;  // (x - dv + 10) mod 512
                int sx1 = (xi + 1 - dv + 522) & 511;
                ushort2 o;
                o.x = f2bf(srow[sx0]);
                o.y = f2bf(srow[sx1]);
                *(ushort2*)(drow + xi) = o;
            }
        }
    }
    if ((blk & 3) == 3) {   // template partial sums: 64 jobs of 8 rows
        int tj = blk >> 2;
        const float* trow = tpl + (size_t)tj * 8 * WW;
        float s1 = 0.f, s2 = 0.f;
        int x = t;
        for (int y = 0; y < 8; ++y) {
            float v = trow[(size_t)y * WW + x];
            s1 += v; s2 += v * v;
        }
        double d1 = (double)s1, d2 = (double)s2;
        for (int off = 32; off; off >>= 1) {
            d1 += __shfl_down(d1, off);
            d2 += __shfl_down(d2, off);
        }
        int lane = t & 63, wv = t >> 6;
        if (lane == 0) { jb1[wv] = d1; jb2[wv] = d2; }
        __syncthreads();
        if (t == 0) {
            double a = 0.0, c = 0.0;
            for (int i = 0; i < 8; ++i) { a += jb1[i]; c += jb2[i]; }
            tplS1p[tj] = a; tplS2p[tj] = c;
        }
    }

    grid.sync();

    // ---------------- P1: correlation MFMA -----------------------------------
    {
        const int l  = t & 63;
        const int w  = t >> 6;           // wave 0..7 (waves 0..6 compute)
        const int kg = l >> 4;
        const int ln = l & 15;
        const int kbA = ((blk & 7) << 6) | (blk >> 3);   // XCD swizzle
#pragma unroll 1
        for (int c = 0; c < 2; ++c) {
            const int kb = kbA + 32 * c;
            const int k0 = kb << 9;
            if (c) __syncthreads();      // WAR on Bs
            // stage frame chunk: f32 -> bf16 interleave into LDS
            for (int i = t; i < 4096; i += 512) {
                int frame = i >> 7, q = i & 127;
                float4 v = *(const float4*)(fr + (size_t)frame * NPIX + k0 + 4 * q);
                int k8 = q >> 1, j4 = (q & 1) * 4;
                ushort4 o;
                o.x = f2bf(v.x); o.y = f2bf(v.y); o.z = f2bf(v.z); o.w = f2bf(v.w);
                *(ushort4*)&Bs[(k8 * 32 + frame) * 8 + j4] = o;
            }
            __syncthreads();
            if (w < 7) {                 // 7 waves x 4 m-tiles = 28 tiles
                const unsigned short *q0, *q1, *q2, *q3;
                {
                    int m_g, du, dv;
                    m_g = 16 * (4 * w + 0) + ln; du = (m_g * 1561) >> 15; dv = m_g - 21 * du;
                    if (m_g >= 441) { du = 0; dv = 0; }
                    q0 = tplv + ((size_t)(dv * 532 + 20 - du) * 512 + 8 * kg + k0);
                    m_g = 16 * (4 * w + 1) + ln; du = (m_g * 1561) >> 15; dv = m_g - 21 * du;
                    if (m_g >= 441) { du = 0; dv = 0; }
                    q1 = tplv + ((size_t)(dv * 532 + 20 - du) * 512 + 8 * kg + k0);
                    m_g = 16 * (4 * w + 2) + ln; du = (m_g * 1561) >> 15; dv = m_g - 21 * du;
                    if (m_g >= 441) { du = 0; dv = 0; }
                    q2 = tplv + ((size_t)(dv * 532 + 20 - du) * 512 + 8 * kg + k0);
                    m_g = 16 * (4 * w + 3) + ln; du = (m_g * 1561) >> 15; dv = m_g - 21 * du;
                    if (m_g >= 441) { du = 0; dv = 0; }
                    q3 = tplv + ((size_t)(dv * 532 + 20 - du) * 512 + 8 * kg + k0);
                }
                const unsigned short* lB = Bs + kg * 256 + ln * 8;
                floatx4 a00 = {}, a01 = {}, a10 = {}, a11 = {};
                floatx4 a20 = {}, a21 = {}, a30 = {}, a31 = {};
#pragma unroll
                for (int ks = 0; ks < 16; ++ks) {
                    short8 A0 = *(const short8*)q0;
                    short8 A1 = *(const short8*)q1;
                    short8 A2 = *(const short8*)q2;
                    short8 A3 = *(const short8*)q3;
                    short8 B0 = *(const short8*)(lB + ks * 1024);
                    short8 B1 = *(const short8*)(lB + ks * 1024 + 128);
                    a00 = __builtin_amdgcn_mfma_f32_16x16x32_bf16(A0, B0, a00, 0, 0, 0);
                    a01 = __builtin_amdgcn_mfma_f32_16x16x32_bf16(A0, B1, a01, 0, 0, 0);
                    a10 = __builtin_amdgcn_mfma_f32_16x16x32_bf16(A1, B0, a10, 0, 0, 0);
                    a11 = __builtin_amdgcn_mfma_f32_16x16x32_bf16(A1, B1, a11, 0, 0, 0);
                    a20 = __builtin_amdgcn_mfma_f32_16x16x32_bf16(A2, B0, a20, 0, 0, 0);
                    a21 = __builtin_amdgcn_mfma_f32_16x16x32_bf16(A2, B1, a21, 0, 0, 0);
                    a30 = __builtin_amdgcn_mfma_f32_16x16x32_bf16(A3, B0, a30, 0, 0, 0);
                    a31 = __builtin_amdgcn_mfma_f32_16x16x32_bf16(A3, B1, a31, 0, 0, 0);
                    q0 += 32; q1 += 32; q2 += 32; q3 += 32;
                }
                // part[((kb*28 + mtile)*32 + n)*16 + mr]
                size_t base = ((size_t)kb * MT28 + 4 * w) * 32;
                floatx4* p;
                p = (floatx4*)(part + (base +       ln) * 16 + 4 * kg); *p = a00;
                p = (floatx4*)(part + (base +  16 + ln) * 16 + 4 * kg); *p = a01;
                p = (floatx4*)(part + (base +  32 + ln) * 16 + 4 * kg); *p = a10;
                p = (floatx4*)(part + (base +  48 + ln) * 16 + 4 * kg); *p = a11;
                p = (floatx4*)(part + (base +  64 + ln) * 16 + 4 * kg); *p = a20;
                p = (floatx4*)(part + (base +  80 + ln) * 16 + 4 * kg); *p = a21;
                p = (floatx4*)(part + (base +  96 + ln) * 16 + 4 * kg); *p = a30;
                p = (floatx4*)(part + (base + 112 + ln) * 16 + 4 * kg); *p = a31;
            }
        }
    }

    grid.sync();

    // ---------------- P2: reduce partials + stage2 denominator ---------------
    if (blk < 224) {
        int oct = blk / 28;                      // 0..7 (64 kb-chunks each)
        int j   = (blk % 28) * 512 + t;          // 0..14335
        const float* p = part + (size_t)(oct * 64) * PARTSZ + j;
        float s = 0.f;
#pragma unroll 8
        for (int i = 0; i < 64; ++i)
            s += p[(size_t)i * PARTSZ];
        cc8[(size_t)oct * PARTSZ + j] = s;       // per-oct partial, no atomic
    } else if (blk < 256) {
        int b = blk - 224;
        int x = t;
        const float* img = fr + (size_t)b * NPIX;
        float top[20], bot[20];
#pragma unroll
        for (int y = 0; y < 20; ++y) top[y] = img[(size_t)y * WW + x];
#pragma unroll
        for (int y = 0; y < 20; ++y) bot[y] = img[(size_t)(492 + y) * WW + x];

        float t1 = 0.f, t2 = 0.f, b1 = 0.f, b2 = 0.f;
#pragma unroll
        for (int y = 0; y < 20; ++y) {
            t1 += top[y]; t2 += top[y] * top[y];
            b1 += bot[y]; b2 += bot[y] * bot[y];
        }
        float i1 = 0.f, i2 = 0.f;
#pragma unroll
        for (int o = 0; o < 8; ++o) {
            i1 += I1p[((size_t)(b * 8 + o)) * 512 + x];
            i2 += I2p[((size_t)(b * 8 + o)) * 512 + x];
        }
        int lane = x & 63, wv = x >> 6;

        // template totals (64 partials -> wave 0)
        if (x < 64) {
            double d1 = tplS1p[x], d2 = tplS2p[x];
            for (int off = 32; off; off >>= 1) {
                d1 += __shfl_down(d1, off);
                d2 += __shfl_down(d2, off);
            }
            if (x == 0) {
                tS1s = d1; tS2s = d2;
                if (blk == 224) { sum1[32] = d1; }
            }
        }

        // frame total -> sum1[b]
        double tot = (double)i1 + (double)t1 + (double)b1;
        for (int off = 32; off; off >>= 1) tot += __shfl_down(tot, off);
        if (lane == 0) wrT[wv] = tot;

        float s1 = i1 + t1, s2 = i2 + t2;
#pragma unroll
        for (int u = 0; u < NS; ++u) {
            if (u) {
                float a = top[u-1], c = bot[u-1];
                s1 += c - a;
                s2 += c * c - a * a;
            }
            double d1 = (double)s1, d2 = (double)s2;
            for (int off = 32; off; off >>= 1) {
                d1 += __shfl_down(d1, off);
                d2 += __shfl_down(d2, off);
            }
            if (lane == 0) { wr1[u][wv] = d1; wr2[u][wv] = d2; }
            if (x < 20)        { e1[u][x]       = s1; e2[u][x]       = s2; }
            else if (x >= 492) { e1[u][x - 472] = s1; e2[u][x - 472] = s2; }
        }
        __syncthreads();
        if (x == 0) {
            double s = 0.0;
            for (int i = 0; i < 8; ++i) s += wrT[i];
            sum1[b] = s;
        }
        if (x < NS) {
            double a = 0.0, c = 0.0;
            for (int i = 0; i < 8; ++i) { a += wr1[x][i]; c += wr2[x][i]; }
            totals1[x] = a; totals2[x] = c;
        }
        __syncthreads();
        if (x < NS * NS) {
            int u = x / NS, v = x - NS * u;
            double S1 = totals1[u], S2 = totals2[u];
            for (int j = 0; j < v; ++j)  { S1 -= (double)e1[u][j];      S2 -= (double)e2[u][j]; }
            for (int j = v; j < 20; ++j) { S1 -= (double)e1[u][20 + j]; S2 -= (double)e2[u][20 + j]; }
            const double inv = 1.0 / ((double)KWIN * (double)KWIN);
            double m1 = S1 * inv, m2 = S2 * inv;
            double var = m2 - (m1 * m1) * inv + 1e-8;   // reference's formula
            if (var < 0.0) var = 0.0;
            double tv = tS2s - tS1s * tS1s * (1.0 / (double)NPIX) + 1e-8;
            denom[(size_t)b * NS * NS + x] = (float)sqrt(tv * var);
        }
    }

    grid.sync();

    // ---------------- P3: argmax + subpixel ----------------------------------
    if (blk < NB && t < 64) {
        int b = blk;
        const float* D = denom + (size_t)b * NS * NS;
        float corr = (float)(sum1[b] * sum1[32] * (1.0 / (double)NPIX));
        auto ccAt = [&](int m) -> float {
            int jj = ((m >> 4) * 512) + b * 16 + (m & 15);
            float s = 0.f;
#pragma unroll
            for (int o = 0; o < 8; ++o) s += cc8[(size_t)o * PARTSZ + jj];
            return s;
        };
        int l = t;
        float best = -1e30f; int bidx = NS * NS;
        for (int i = l; i < NS * NS; i += 64) {
            float v = fabsf(ccAt(i) - corr) / D[i];
            if (v != v) v = 0.f;               // NaN -> 0 (matches reference)
            if (v > best) { best = v; bidx = i; }
        }
        for (int off = 32; off; off >>= 1) {
            float ov = __shfl_down(best, off);
            int   oi = __shfl_down(bidx, off);
            if (ov > best || (ov == best && oi < bidx)) { best = ov; bidx = oi; }
        }
        if (l == 0) {
            int shx = bidx / NS, shy = bidx % NS;
            auto nccAt = [&](int i, int j) -> float {
                i = (i < 0) ? i + NS : i; i = (i > NS - 1) ? NS - 1 : i;  // jnp wrap-then-clamp
                j = (j < 0) ? j + NS : j; j = (j > NS - 1) ? NS - 1 : j;
                float v = fabsf(ccAt(i * NS + j) - corr) / D[i * NS + j];
                if (v != v) v = 0.f;
                return v;
            };
            float lc  = logf(nccAt(shx, shy));
            float lxm = logf(nccAt(shx - 1, shy));
            float lxp = logf(nccAt(shx + 1, shy));
            float lym = logf(nccAt(shx, shy - 1));
            float lyp = logf(nccAt(shx, shy + 1));
            float shxn = -(float)(shx - 10) - (lxm - lxp) / (2.f * lxm - 4.f * lc + 2.f * lxp);
            float shyn = -(float)(shy - 10) - (lym - lyp) / (2.f * lym - 4.f * lc + 2.f * lyp);
            shifts[b]      = shxn;   // dy
            shifts[32 + b] = shyn;   // dx
        }
    }

    grid.sync();

    // ---------------- P4: bilinear warp + transposed write -------------------
    {
        int g   = t >> 8;                 // group 0/1 (waves 0-3 / 4-7)
        int tid = t & 255;
        int tx  = tid & 31;
        int tz  = tid >> 5;
#pragma unroll 1
        for (int it = 0; it < 16; ++it) {
            int J = (blk * 2 + g) * 16 + it;      // 0..8191
            int b    = J >> 8;
            int tile = J & 255;
            int h0 = (tile >> 4) * 32;
            int w0 = (tile & 15) * 32;
            float dy = shifts[b], dx = shifts[32 + b];
            const float* img = fr + (size_t)b * NPIX;
#pragma unroll
            for (int s = 0; s < 4; ++s) {
                int h = h0 + tz + 8 * s;
                int w = w0 + tx;
                float yq = (float)h - dy;
                float xq = (float)w - dx;
                float y0f = floorf(yq), x0f = floorf(xq);
                float wy = yq - y0f, wx = xq - x0f;
                int y0 = (int)y0f, x0 = (int)x0f;
                bool vy0 = (y0 >= 0) & (y0 < HH), vy1 = (y0+1 >= 0) & (y0+1 < HH);
                bool vx0 = (x0 >= 0) & (x0 < WW), vx1 = (x0+1 >= 0) & (x0+1 < WW);
                int y0c = min(max(y0, 0), HH-1), y1c = min(max(y0+1, 0), HH-1);
                int x0c = min(max(x0, 0), WW-1), x1c = min(max(x0+1, 0), WW-1);
                float v00 = (vy0 & vx0) ? img[(size_t)y0c * WW + x0c] : 0.f;
                float v01 = (vy0 & vx1) ? img[(size_t)y0c * WW + x1c] : 0.f;
                float v10 = (vy1 & vx0) ? img[(size_t)y1c * WW + x0c] : 0.f;
                float v11 = (vy1 & vx1) ? img[(size_t)y1c * WW + x1c] : 0.f;
                float val = v00 * (1.f - wy) * (1.f - wx) + v01 * (1.f - wy) * wx
                          + v10 * wy * (1.f - wx)         + v11 * wy * wx;
                tile2[g][tz + 8 * s][tx] = val;
            }
            __syncthreads();
#pragma unroll
            for (int s = 0; s < 4; ++s) {
                int hh = tx;
                int ww = tz + 8 * s;
                out[(size_t)b * NPIX + (size_t)(w0 + ww) * HH + (h0 + hh)] = tile2[g][hh][ww];
            }
            __syncthreads();              // WAR before next iteration
        }
    }
}

// ---------------- launch ----------------------------------------------------
extern "C" void kernel_launch(void* const* d_in, const int* in_sizes, int n_in,
                              void* d_out, int out_size, void* d_ws, size_t ws_size,
                              hipStream_t stream) {
    const float* fr  = (const float*)d_in[0];   // (1,32,512,512,1) flat
    const float* tpl = (const float*)d_in[1];   // (512,512)
    float* out = (float*)d_out;
    char* ws = (char*)d_ws;

    // ws layout (~52 MB), all buffers fully written before read -> no memset
    unsigned short* tplv = (unsigned short*)(ws + 0);              // 11.44 MB
    float*  part   = (float*) (ws + 16777216);                     // 29.36 MB
    float*  cc8    = (float*) (ws + 50331648);                     // 458 KB
    float*  I1p    = (float*) (ws + 51380224);                     // 512 KB
    float*  I2p    = (float*) (ws + 52428800);                     // 512 KB
    double* tplS1p = (double*)(ws + 53477376);                     // 512 B
    double* tplS2p = (double*)(ws + 53481472);                     // 512 B
    double* sum1   = (double*)(ws + 53485568);                     // 33 doubles
    float*  denom  = (float*) (ws + 53501952);                     // 56 KB
    float*  shifts = (float*) (ws + 53608448);                     // 64 floats

    void* kargs[] = {
        (void*)&fr, (void*)&tpl, (void*)&tplv, (void*)&part, (void*)&cc8,
        (void*)&I1p, (void*)&I2p, (void*)&tplS1p, (void*)&tplS2p,
        (void*)&sum1, (void*)&denom, (void*)&shifts, (void*)&out
    };
    hipLaunchCooperativeKernel((void*)motion_all, dim3(256), dim3(512),
                               kargs, 0, stream);
}

// Round 7
// 177.561 us; speedup vs baseline: 1.7357x; 1.7357x over previous
//
#include <hip/hip_runtime.h>
#include <math.h>

#define HH 512
#define WW 512
#define NPIX (HH*WW)
#define NB 32
#define NS 21           // 2*MS+1 shifts per axis
#define KWIN 492        // window size (H - 2*10)
#define MT28 28         // m-tiles (448 = 28*16, M=441 padded)
#define PARTSZ (MT28*32*16)   // 14336 floats per k-chunk
#define TPLB_COPY 278528      // 512*544 shorts per parity copy

typedef __attribute__((ext_vector_type(8))) short short8;
typedef __attribute__((ext_vector_type(4))) float floatx4;

__device__ __forceinline__ unsigned short f2bf(float f) {
    unsigned u = __float_as_uint(f);
    unsigned r = (u + 0x7fffu + ((u >> 16) & 1u)) >> 16;
    return (unsigned short)r;
}

// 16B fragment load from a 4B-aligned address (tplb cols are even, not x8):
// explicit dword loads keep the compiler honest about alignment.
__device__ __forceinline__ short8 loadA(const unsigned short* p) {
    union { short8 v; unsigned u[4]; } r;
    const unsigned* q = (const unsigned*)p;
    r.u[0] = q[0]; r.u[1] = q[1]; r.u[2] = q[2]; r.u[3] = q[3];
    return r.v;
}

// ---------------- prep: interior col partial sums (256 blk), template partial
//   sums (64 blk), padded bf16 template (128 blk), flag zero. No atomics.
__global__ __launch_bounds__(512) void prep(
    const float* __restrict__ fr, const float* __restrict__ tpl,
    unsigned short* __restrict__ tplb,
    float* __restrict__ I1p, float* __restrict__ I2p,
    double* __restrict__ tplS1p, double* __restrict__ tplS2p,
    int* __restrict__ flag)
{
    int blk = blockIdx.x;
    int t   = threadIdx.x;
    if (blk == 0 && t == 0) *flag = 0;

    if (blk < 256) {
        // interior column partial sums: (frame b, row-oct) -> I1p/I2p
        int b = blk >> 3, oct = blk & 7;              // b in [0,32)
        const float* img = fr + (size_t)b * NPIX;
        int x = t;
        float s1 = 0.f, s2 = 0.f;
        int y0 = 20 + 59 * oct;                       // rows 20..491 = 8*59
        for (int y = y0; y < y0 + 59; ++y) {
            float v = img[(size_t)y * WW + x];
            s1 += v; s2 += v * v;
        }
        I1p[(size_t)blk * 512 + x] = s1;
        I2p[(size_t)blk * 512 + x] = s2;
    } else if (blk < 320) {
        // template partial sums: 64 jobs of 8 rows
        __shared__ double jb1[8], jb2[8];
        int tj = blk - 256;
        const float* trow = tpl + (size_t)tj * 8 * WW;
        float s1 = 0.f, s2 = 0.f;
        int x = t;
        for (int y = 0; y < 8; ++y) {
            float v = trow[(size_t)y * WW + x];
            s1 += v; s2 += v * v;
        }
        double d1 = (double)s1, d2 = (double)s2;
        for (int off = 32; off; off >>= 1) {
            d1 += __shfl_down(d1, off);
            d2 += __shfl_down(d2, off);
        }
        int lane = t & 63, wv = t >> 6;
        if (lane == 0) { jb1[wv] = d1; jb2[wv] = d2; }
        __syncthreads();
        if (t == 0) {
            double a = 0.0, c = 0.0;
            for (int i = 0; i < 8; ++i) { a += jb1[i]; c += jb2[i]; }
            tplS1p[tj] = a; tplS2p[tj] = c;
        }
    } else {
        // padded bf16 template: copyP[sy][c] = bf16(tpl[sy][(c-16-P) mod 512])
        int sy0 = (blk - 320) * 4;                    // 128 blocks x 4 rows
#pragma unroll
        for (int rr = 0; rr < 4; ++rr) {
            int sy = sy0 + rr;
            const float* srow = tpl + (size_t)sy * WW;
#pragma unroll
            for (int P = 0; P < 2; ++P) {
                for (int c = t; c < 544; c += 512) {
                    int sx = (c + 496 - P) & 511;     // (c-16-P) mod 512
                    tplb[(size_t)P * TPLB_COPY + (size_t)sy * 544 + c] = f2bf(srow[sx]);
                }
            }
        }
    }
}

// ---------------- Kernel C: implicit-GEMM correlation via MFMA --------------
// 512 chunks of 512 k (= one image row y=kb of all 32 frames). One block per
// chunk: 896 thr = 14 waves x 2 m-tiles = 28 tiles. B chunk read directly
// from fr (f32 float4, coalesced), bf16-converted into LDS. A fragments read
// from the 1.1 MB padded template (L2-hot): element for tile row m_g
// (du=m_g/21, dv=m_g%21), k=(y=kb, x) is
//   tpl[(kb+10-du) mod 512][(x+10-dv) mod 512]
//     = tplb[P=dv&1][(kb+522-du)&511][x - dv + 26 + P]   (4B-aligned).
__global__ __launch_bounds__(896) void corr_mfma(
    const float* __restrict__ fr,
    const unsigned short* __restrict__ tplb,
    float* __restrict__ part)
{
    __shared__ unsigned short Bs[16384];   // [k8][frame][8] : 512k x 32fr, 32 KB

    const int t   = threadIdx.x;
    const int l   = t & 63;
    const int wid = t >> 6;               // wave 0..13 = tile-pair
    const int idx = blockIdx.x;           // 0..511
    const int kb  = ((idx & 7) << 6) | (idx >> 3);   // XCD swizzle
    const int k0  = kb << 9;              // k-chunk base (512 each)
    const int kg  = l >> 4;               // k-group 0..3
    const int ln  = l & 15;

    // fused conv: fr slice -> bf16 interleave in LDS (coalesced 16B loads)
    for (int i = t; i < 4096; i += 896) {
        int frame = i >> 7, q = i & 127;
        float4 v = *(const float4*)(fr + (size_t)frame * NPIX + k0 + 4 * q);
        int k8 = q >> 1, j4 = (q & 1) * 4;
        ushort4 o;
        o.x = f2bf(v.x); o.y = f2bf(v.y); o.z = f2bf(v.z); o.w = f2bf(v.w);
        *(ushort4*)&Bs[(k8 * 32 + frame) * 8 + j4] = o;
    }

    const unsigned short* pA0;
    const unsigned short* pA1;
    {
        int m_g = 32 * wid + ln;           // mt = 0
        int du  = (m_g * 1561) >> 15;      // m_g/21 exact for m_g<=447
        int dv  = m_g - 21 * du;
        if (m_g >= 441) { du = 0; dv = 0; }   // pad rows: loaded, never used
        int P   = dv & 1;
        pA0 = tplb + (size_t)P * TPLB_COPY
            + (size_t)((kb + 522 - du) & 511) * 544 + (8 * kg - dv + 26 + P);
        m_g = 32 * wid + 16 + ln;          // mt = 1
        du  = (m_g * 1561) >> 15;
        dv  = m_g - 21 * du;
        if (m_g >= 441) { du = 0; dv = 0; }
        P   = dv & 1;
        pA1 = tplb + (size_t)P * TPLB_COPY
            + (size_t)((kb + 522 - du) & 511) * 544 + (8 * kg - dv + 26 + P);
    }

    const unsigned short* lB = Bs + kg * 256 + ln * 8;

    __syncthreads();

    floatx4 acc00 = {}, acc01 = {}, acc10 = {}, acc11 = {};

#pragma unroll
    for (int ks = 0; ks < 16; ++ks) {      // 16 steps x 32 k = 512
        short8 A0 = loadA(pA0);
        short8 A1 = loadA(pA1);
        short8 B0 = *(const short8*)(lB + ks * 1024);         // frames 0..15
        short8 B1 = *(const short8*)(lB + ks * 1024 + 128);   // frames 16..31
        acc00 = __builtin_amdgcn_mfma_f32_16x16x32_bf16(A0, B0, acc00, 0, 0, 0);
        acc01 = __builtin_amdgcn_mfma_f32_16x16x32_bf16(A0, B1, acc01, 0, 0, 0);
        acc10 = __builtin_amdgcn_mfma_f32_16x16x32_bf16(A1, B0, acc10, 0, 0, 0);
        acc11 = __builtin_amdgcn_mfma_f32_16x16x32_bf16(A1, B1, acc11, 0, 0, 0);
        pA0 += 32; pA1 += 32;
    }

    // dense partial stores: part[((kb*28 + mtile)*32 + n)*16 + mr], mr=4kg+r
    {
        size_t base = ((size_t)kb * MT28 + 2 * wid) * 32;
        floatx4* p;
        p = (floatx4*)(part + (base + ln)      * 16 + 4 * kg); *p = acc00;
        p = (floatx4*)(part + (base + 16 + ln) * 16 + 4 * kg); *p = acc01;
        p = (floatx4*)(part + (base + 32 + ln) * 16 + 4 * kg); *p = acc10;
        p = (floatx4*)(part + (base + 48 + ln) * 16 + 4 * kg); *p = acc11;
    }
}

// ---------------- reduce partials + stage2 denominator + fused argmax -------
// blocks [0,224):  reduce part -> cc8 (disjoint, no atomics), then
//                  threadfence (L2 writeback) + flag++.
// blocks [224,256): stage2 for frame b = blk-224 (denominators in LDS),
//                  spin until flag==224, threadfence (acquire), then
//                  argmax + subpixel -> shifts.
// Deadlock-free: grid 256 <= 256 CUs, all blocks co-resident; waiters only
// wait on non-waiting blocks.
__global__ __launch_bounds__(512) void reduce_am(
    const float* __restrict__ part, float* __restrict__ cc8,
    const float* __restrict__ fr, const float* __restrict__ I1p,
    const float* __restrict__ I2p, const double* __restrict__ tplS1p,
    const double* __restrict__ tplS2p, int* __restrict__ flag,
    float* __restrict__ shifts)
{
    int blk = blockIdx.x;
    int t   = threadIdx.x;

    if (blk < 224) {
        int oct = blk / 28;                      // 0..7 (64 kb-chunks each)
        int j   = (blk % 28) * 512 + t;          // 0..14335
        const float* p = part + (size_t)(oct * 64) * PARTSZ + j;
        float s = 0.f;
#pragma unroll 8
        for (int i = 0; i < 64; ++i)
            s += p[(size_t)i * PARTSZ];
        cc8[(size_t)oct * PARTSZ + j] = s;       // per-oct partial, no atomic
        __threadfence();                          // release: L2 writeback
        __syncthreads();
        if (t == 0) atomicAdd(flag, 1);
        return;
    }

    __shared__ double wr1[NS][8], wr2[NS][8], wrT[8];
    __shared__ float  e1[NS][40], e2[NS][40];
    __shared__ double totals1[NS], totals2[NS];
    __shared__ float  denomS[NS * NS];
    __shared__ double tS1s, tS2s, sum1b;

    int b = blk - 224;
    int x = t;
    const float* img = fr + (size_t)b * NPIX;
    float top[20], bot[20];
#pragma unroll
    for (int y = 0; y < 20; ++y) top[y] = img[(size_t)y * WW + x];
#pragma unroll
    for (int y = 0; y < 20; ++y) bot[y] = img[(size_t)(492 + y) * WW + x];

    float t1 = 0.f, t2 = 0.f, b1 = 0.f, b2 = 0.f;
#pragma unroll
    for (int y = 0; y < 20; ++y) {
        t1 += top[y]; t2 += top[y] * top[y];
        b1 += bot[y]; b2 += bot[y] * bot[y];
    }
    float i1 = 0.f, i2 = 0.f;
#pragma unroll
    for (int o = 0; o < 8; ++o) {
        i1 += I1p[((size_t)(b * 8 + o)) * 512 + x];
        i2 += I2p[((size_t)(b * 8 + o)) * 512 + x];
    }
    int lane = x & 63, wv = x >> 6;

    // template totals (64 partials -> wave 0)
    if (x < 64) {
        double d1 = tplS1p[x], d2 = tplS2p[x];
        for (int off = 32; off; off >>= 1) {
            d1 += __shfl_down(d1, off);
            d2 += __shfl_down(d2, off);
        }
        if (x == 0) { tS1s = d1; tS2s = d2; }
    }

    // frame total
    double tot = (double)i1 + (double)t1 + (double)b1;
    for (int off = 32; off; off >>= 1) tot += __shfl_down(tot, off);
    if (lane == 0) wrT[wv] = tot;

    // per-u column-window sums (register sliding), block totals + edge cols
    float s1 = i1 + t1, s2 = i2 + t2;
#pragma unroll
    for (int u = 0; u < NS; ++u) {
        if (u) {
            float a = top[u-1], c = bot[u-1];
            s1 += c - a;
            s2 += c * c - a * a;
        }
        double d1 = (double)s1, d2 = (double)s2;
        for (int off = 32; off; off >>= 1) {
            d1 += __shfl_down(d1, off);
            d2 += __shfl_down(d2, off);
        }
        if (lane == 0) { wr1[u][wv] = d1; wr2[u][wv] = d2; }
        if (x < 20)        { e1[u][x]       = s1; e2[u][x]       = s2; }
        else if (x >= 492) { e1[u][x - 472] = s1; e2[u][x - 472] = s2; }
    }
    __syncthreads();
    if (x == 0) {
        double s = 0.0;
        for (int i = 0; i < 8; ++i) s += wrT[i];
        sum1b = s;
    }
    if (x < NS) {
        double a = 0.0, c = 0.0;
        for (int i = 0; i < 8; ++i) { a += wr1[x][i]; c += wr2[x][i]; }
        totals1[x] = a; totals2[x] = c;
    }
    __syncthreads();
    if (x < NS * NS) {
        int u = x / NS, v = x - NS * u;
        double S1 = totals1[u], S2 = totals2[u];
        for (int j = 0; j < v; ++j)  { S1 -= (double)e1[u][j];      S2 -= (double)e2[u][j]; }
        for (int j = v; j < 20; ++j) { S1 -= (double)e1[u][20 + j]; S2 -= (double)e2[u][20 + j]; }
        const double inv = 1.0 / ((double)KWIN * (double)KWIN);
        double m1 = S1 * inv, m2 = S2 * inv;
        double var = m2 - (m1 * m1) * inv + 1e-8;   // reference's formula
        if (var < 0.0) var = 0.0;
        double tv = tS2s - tS1s * tS1s * (1.0 / (double)NPIX) + 1e-8;
        denomS[x] = (float)sqrt(tv * var);
    }
    __syncthreads();

    // wait for all reducer blocks (device-scope), then argmax + subpixel
    if (t == 0) {
        while (__hip_atomic_load(flag, __ATOMIC_ACQUIRE,
                                 __HIP_MEMORY_SCOPE_AGENT) < 224)
            __builtin_amdgcn_s_sleep(2);
    }
    __syncthreads();
    __threadfence();                              // acquire: invalidate L2

    if (t < 64) {
        float corr = (float)(sum1b * tS1s * (1.0 / (double)NPIX));
        auto ccAt = [&](int m) -> float {
            int jj = ((m >> 4) * 512) + b * 16 + (m & 15);
            float s = 0.f;
#pragma unroll
            for (int o = 0; o < 8; ++o) s += cc8[(size_t)o * PARTSZ + jj];
            return s;
        };
        float best = -1e30f; int bidx = NS * NS;
        for (int i = t; i < NS * NS; i += 64) {
            float v = fabsf(ccAt(i) - corr) / denomS[i];
            if (v != v) v = 0.f;               // NaN -> 0 (matches reference)
            if (v > best) { best = v; bidx = i; }
        }
        for (int off = 32; off; off >>= 1) {
            float ov = __shfl_down(best, off);
            int   oi = __shfl_down(bidx, off);
            if (ov > best || (ov == best && oi < bidx)) { best = ov; bidx = oi; }
        }
        if (t == 0) {
            int shx = bidx / NS, shy = bidx % NS;
            auto nccAt = [&](int i, int j) -> float {
                i = (i < 0) ? i + NS : i; i = (i > NS - 1) ? NS - 1 : i;  // jnp wrap-then-clamp
                j = (j < 0) ? j + NS : j; j = (j > NS - 1) ? NS - 1 : j;
                float v = fabsf(ccAt(i * NS + j) - corr) / denomS[i * NS + j];
                if (v != v) v = 0.f;
                return v;
            };
            float lc  = logf(nccAt(shx, shy));
            float lxm = logf(nccAt(shx - 1, shy));
            float lxp = logf(nccAt(shx + 1, shy));
            float lym = logf(nccAt(shx, shy - 1));
            float lyp = logf(nccAt(shx, shy + 1));
            float shxn = -(float)(shx - 10) - (lxm - lxp) / (2.f * lxm - 4.f * lc + 2.f * lxp);
            float shyn = -(float)(shy - 10) - (lym - lyp) / (2.f * lym - 4.f * lc + 2.f * lyp);
            shifts[b]      = shxn;   // dy
            shifts[32 + b] = shyn;   // dx
        }
    }
}

// ---------------- Kernel B: bilinear warp + transposed write ----------------
__device__ __forceinline__ float samp(const float* __restrict__ img, int y, int x) {
    bool valid = (y >= 0) & (y < HH) & (x >= 0) & (x < WW);
    int yc = min(max(y, 0), HH - 1), xc = min(max(x, 0), WW - 1);
    float v = img[(size_t)yc * WW + xc];
    return valid ? v : 0.f;
}

__global__ __launch_bounds__(256) void warp_kernel(
    const float* __restrict__ fr, const float* __restrict__ shifts,
    float* __restrict__ out)
{
    int b  = blockIdx.z;
    int h0 = blockIdx.y * 32;
    int w0 = blockIdx.x * 32;
    float dy = shifts[b], dx = shifts[32 + b];
    const float* img = fr + (size_t)b * NPIX;
    __shared__ float tile[32][33];
    int tx = threadIdx.x & 31;
    int tz = threadIdx.x >> 5;
#pragma unroll
    for (int s = 0; s < 4; ++s) {
        int h = h0 + tz + 8 * s;
        int w = w0 + tx;
        float yq = (float)h - dy;
        float xq = (float)w - dx;
        float y0f = floorf(yq), x0f = floorf(xq);
        float wy = yq - y0f, wx = xq - x0f;
        int y0 = (int)y0f, x0 = (int)x0f;
        float v00 = samp(img, y0,     x0);
        float v01 = samp(img, y0,     x0 + 1);
        float v10 = samp(img, y0 + 1, x0);
        float v11 = samp(img, y0 + 1, x0 + 1);
        float val = v00 * (1.f - wy) * (1.f - wx) + v01 * (1.f - wy) * wx
                  + v10 * wy * (1.f - wx)         + v11 * wy * wx;
        tile[tz + 8 * s][tx] = val;
    }
    __syncthreads();
#pragma unroll
    for (int s = 0; s < 4; ++s) {
        int hh = tx;
        int ww = tz + 8 * s;
        out[(size_t)b * NPIX + (size_t)(w0 + ww) * HH + (h0 + hh)] = tile[hh][ww];
    }
}

// ---------------- launch ----------------------------------------------------
extern "C" void kernel_launch(void* const* d_in, const int* in_sizes, int n_in,
                              void* d_out, int out_size, void* d_ws, size_t ws_size,
                              hipStream_t stream) {
    const float* fr  = (const float*)d_in[0];   // (1,32,512,512,1) flat
    const float* tpl = (const float*)d_in[1];   // (512,512)
    float* out = (float*)d_out;
    char* ws = (char*)d_ws;

    // ws layout (~38 MB), every buffer fully rewritten each launch -> no memset
    unsigned short* tplb = (unsigned short*)(ws + 0);        // 1.11 MB (2 copies)
    float*  I1p    = (float*) (ws + 2097152);                // 512 KB (256*512 f)
    float*  I2p    = (float*) (ws + 2621440);                // 512 KB
    double* tplS1p = (double*)(ws + 3145728);                // 512 B
    double* tplS2p = (double*)(ws + 3146240);                // 512 B
    float*  shifts = (float*) (ws + 3146752);                // 256 B
    int*    flag   = (int*)   (ws + 3147264);                // 4 B
    float*  cc8    = (float*) (ws + 4194304);                // 458 KB
    float*  part   = (float*) (ws + 8388608);                // 29.36 MB

    prep     <<<448, 512, 0, stream>>>(fr, tpl, tplb, I1p, I2p, tplS1p, tplS2p, flag);
    corr_mfma<<<512, 896, 0, stream>>>(fr, tplb, part);
    reduce_am<<<256, 512, 0, stream>>>(part, cc8, fr, I1p, I2p, tplS1p, tplS2p, flag, shifts);
    warp_kernel<<<dim3(16, 16, 32), 256, 0, stream>>>(fr, shifts, out);
}

// Round 8
// 169.492 us; speedup vs baseline: 1.8183x; 1.0476x over previous
//
#include <hip/hip_runtime.h>
#include <math.h>

#define HH 512
#define WW 512
#define NPIX (HH*WW)
#define NB 32
#define NS 21           // 2*MS+1 shifts per axis
#define KWIN 492        // window size (H - 2*10)
#define NKB 256         // split-K chunks (1024 k each)
#define MT28 28         // m-tiles (448 = 28*16, M=441 padded)
#define PARTSZ (MT28*32*16)   // 14336 floats per k-chunk
#define TPLB_COPY 278528      // 512*544 shorts per parity copy

typedef __attribute__((ext_vector_type(8))) short short8;
typedef __attribute__((ext_vector_type(4))) float floatx4;

__device__ __forceinline__ unsigned short f2bf(float f) {
    unsigned u = __float_as_uint(f);
    unsigned r = (u + 0x7fffu + ((u >> 16) & 1u)) >> 16;
    return (unsigned short)r;
}

// 16B fragment load from a 4B-aligned address (tplb cols are even, not x8).
__device__ __forceinline__ short8 loadA(const unsigned short* p) {
    union { short8 v; unsigned u[4]; } r;
    const unsigned* q = (const unsigned*)p;
    r.u[0] = q[0]; r.u[1] = q[1]; r.u[2] = q[2]; r.u[3] = q[3];
    return r.v;
}

// ---------------- prep: interior col partial sums (256 blk), template partial
//   sums (64 blk), padded bf16 template (128 blk), flag zero. No atomics.
__global__ __launch_bounds__(512) void prep(
    const float* __restrict__ fr, const float* __restrict__ tpl,
    unsigned short* __restrict__ tplb,
    float* __restrict__ I1p, float* __restrict__ I2p,
    double* __restrict__ tplS1p, double* __restrict__ tplS2p,
    int* __restrict__ flag)
{
    int blk = blockIdx.x;
    int t   = threadIdx.x;
    if (blk == 0 && t == 0) *flag = 0;

    if (blk < 256) {
        // interior column partial sums: (frame b, row-oct) -> I1p/I2p
        int b = blk >> 3, oct = blk & 7;              // b in [0,32)
        const float* img = fr + (size_t)b * NPIX;
        int x = t;
        float s1 = 0.f, s2 = 0.f;
        int y0 = 20 + 59 * oct;                       // rows 20..491 = 8*59
        for (int y = y0; y < y0 + 59; ++y) {
            float v = img[(size_t)y * WW + x];
            s1 += v; s2 += v * v;
        }
        I1p[(size_t)blk * 512 + x] = s1;
        I2p[(size_t)blk * 512 + x] = s2;
    } else if (blk < 320) {
        // template partial sums: 64 jobs of 8 rows
        __shared__ double jb1[8], jb2[8];
        int tj = blk - 256;
        const float* trow = tpl + (size_t)tj * 8 * WW;
        float s1 = 0.f, s2 = 0.f;
        int x = t;
        for (int y = 0; y < 8; ++y) {
            float v = trow[(size_t)y * WW + x];
            s1 += v; s2 += v * v;
        }
        double d1 = (double)s1, d2 = (double)s2;
        for (int off = 32; off; off >>= 1) {
            d1 += __shfl_down(d1, off);
            d2 += __shfl_down(d2, off);
        }
        int lane = t & 63, wv = t >> 6;
        if (lane == 0) { jb1[wv] = d1; jb2[wv] = d2; }
        __syncthreads();
        if (t == 0) {
            double a = 0.0, c = 0.0;
            for (int i = 0; i < 8; ++i) { a += jb1[i]; c += jb2[i]; }
            tplS1p[tj] = a; tplS2p[tj] = c;
        }
    } else {
        // padded bf16 template: copyP[sy][c] = bf16(tpl[sy][(c-16-P) mod 512])
        int sy0 = (blk - 320) * 4;                    // 128 blocks x 4 rows
#pragma unroll
        for (int rr = 0; rr < 4; ++rr) {
            int sy = sy0 + rr;
            const float* srow = tpl + (size_t)sy * WW;
#pragma unroll
            for (int P = 0; P < 2; ++P) {
                for (int c = t; c < 544; c += 512) {
                    int sx = (c + 496 - P) & 511;     // (c-16-P) mod 512
                    tplb[(size_t)P * TPLB_COPY + (size_t)sy * 544 + c] = f2bf(srow[sx]);
                }
            }
        }
    }
}

// ---------------- Kernel C: implicit-GEMM correlation via MFMA --------------
// NKB=256 chunks of 1024 k (= 2 image rows of all 32 frames). One block per
// chunk: 896 thr = 14 waves x 2 m-tiles. Two 512-k sub-chunks staged into LDS
// sequentially, ACCUMULATING in registers (halves part traffic both ends).
// A fragments read from the 1.1 MB padded template (L2-hot):
//   tplb[P=dv&1][(row + 522 - du)&511][x - dv + 26 + P], row = 2*kb + c.
__global__ __launch_bounds__(896) void corr_mfma(
    const float* __restrict__ fr,
    const unsigned short* __restrict__ tplb,
    float* __restrict__ part)
{
    __shared__ unsigned short Bs[16384];   // [k8][frame][8] : 512k x 32fr, 32 KB

    const int t   = threadIdx.x;
    const int l   = t & 63;
    const int wid = t >> 6;               // wave 0..13 = tile-pair
    const int idx = blockIdx.x;           // 0..255
    const int kb  = ((idx & 7) << 5) | (idx >> 3);   // XCD swizzle (32/XCD)
    const int kg  = l >> 4;               // k-group 0..3
    const int ln  = l & 15;

    // m-geometry (sub-chunk independent)
    int du0, dv0, du1, dv1;
    {
        int m_g = 32 * wid + ln;           // mt = 0
        du0 = (m_g * 1561) >> 15;          // m_g/21 exact for m_g<=447
        dv0 = m_g - 21 * du0;
        if (m_g >= 441) { du0 = 0; dv0 = 0; }   // pad rows: loaded, never used
        m_g = 32 * wid + 16 + ln;          // mt = 1
        du1 = (m_g * 1561) >> 15;
        dv1 = m_g - 21 * du1;
        if (m_g >= 441) { du1 = 0; dv1 = 0; }
    }
    const int P0 = dv0 & 1, P1 = dv1 & 1;
    const int col0 = 8 * kg - dv0 + 26 + P0;
    const int col1 = 8 * kg - dv1 + 26 + P1;

    const unsigned short* lB = Bs + kg * 256 + ln * 8;

    floatx4 acc00 = {}, acc01 = {}, acc10 = {}, acc11 = {};

#pragma unroll 1
    for (int c = 0; c < 2; ++c) {
        const int row = 2 * kb + c;          // template/frame image row
        const int k0  = row << 9;            // global k base of this sub-chunk
        if (c) __syncthreads();              // WAR on Bs
        // stage: fr slice -> bf16 interleave in LDS (coalesced 16B loads)
        for (int i = t; i < 4096; i += 896) {
            int frame = i >> 7, q = i & 127;
            float4 v = *(const float4*)(fr + (size_t)frame * NPIX + k0 + 4 * q);
            int k8 = q >> 1, j4 = (q & 1) * 4;
            ushort4 o;
            o.x = f2bf(v.x); o.y = f2bf(v.y); o.z = f2bf(v.z); o.w = f2bf(v.w);
            *(ushort4*)&Bs[(k8 * 32 + frame) * 8 + j4] = o;
        }
        __syncthreads();

        const unsigned short* pA0 = tplb + (size_t)P0 * TPLB_COPY
            + (size_t)((row + 522 - du0) & 511) * 544 + col0;
        const unsigned short* pA1 = tplb + (size_t)P1 * TPLB_COPY
            + (size_t)((row + 522 - du1) & 511) * 544 + col1;

#pragma unroll
        for (int ks = 0; ks < 16; ++ks) {    // 16 steps x 32 k = 512
            short8 A0 = loadA(pA0);
            short8 A1 = loadA(pA1);
            short8 B0 = *(const short8*)(lB + ks * 1024);         // frames 0..15
            short8 B1 = *(const short8*)(lB + ks * 1024 + 128);   // frames 16..31
            acc00 = __builtin_amdgcn_mfma_f32_16x16x32_bf16(A0, B0, acc00, 0, 0, 0);
            acc01 = __builtin_amdgcn_mfma_f32_16x16x32_bf16(A0, B1, acc01, 0, 0, 0);
            acc10 = __builtin_amdgcn_mfma_f32_16x16x32_bf16(A1, B0, acc10, 0, 0, 0);
            acc11 = __builtin_amdgcn_mfma_f32_16x16x32_bf16(A1, B1, acc11, 0, 0, 0);
            pA0 += 32; pA1 += 32;
        }
    }

    // dense partial stores: part[((kb*28 + mtile)*32 + n)*16 + mr], mr=4kg+r
    {
        size_t base = ((size_t)kb * MT28 + 2 * wid) * 32;
        floatx4* p;
        p = (floatx4*)(part + (base + ln)      * 16 + 4 * kg); *p = acc00;
        p = (floatx4*)(part + (base + 16 + ln) * 16 + 4 * kg); *p = acc01;
        p = (floatx4*)(part + (base + 32 + ln) * 16 + 4 * kg); *p = acc10;
        p = (floatx4*)(part + (base + 48 + ln) * 16 + 4 * kg); *p = acc11;
    }
}

// ---------------- reduce partials + stage2 denominator + fused argmax -------
// blocks [0,224):  reduce part -> cc8 (disjoint, no atomics), then
//                  threadfence (release) + flag++.
// blocks [224,256): stage2 for frame b (denominators in LDS), RELAXED spin
//                  with s_sleep back-off until flag==224, ONE threadfence
//                  (acquire), then argmax + subpixel -> shifts.
__global__ __launch_bounds__(512) void reduce_am(
    const float* __restrict__ part, float* __restrict__ cc8,
    const float* __restrict__ fr, const float* __restrict__ I1p,
    const float* __restrict__ I2p, const double* __restrict__ tplS1p,
    const double* __restrict__ tplS2p, int* __restrict__ flag,
    float* __restrict__ shifts)
{
    int blk = blockIdx.x;
    int t   = threadIdx.x;

    if (blk < 224) {
        int oct = blk / 28;                      // 0..7 (32 kb-chunks each)
        int j   = (blk % 28) * 512 + t;          // 0..14335
        const float* p = part + (size_t)(oct * 32) * PARTSZ + j;
        float s = 0.f;
#pragma unroll 8
        for (int i = 0; i < 32; ++i)
            s += p[(size_t)i * PARTSZ];
        cc8[(size_t)oct * PARTSZ + j] = s;       // per-oct partial, no atomic
        __threadfence();                          // release: writes visible
        __syncthreads();
        if (t == 0) atomicAdd(flag, 1);
        return;
    }

    __shared__ double wr1[NS][8], wr2[NS][8], wrT[8];
    __shared__ float  e1[NS][40], e2[NS][40];
    __shared__ double totals1[NS], totals2[NS];
    __shared__ float  denomS[NS * NS];
    __shared__ double tS1s, tS2s, sum1b;

    int b = blk - 224;
    int x = t;
    const float* img = fr + (size_t)b * NPIX;
    float top[20], bot[20];
#pragma unroll
    for (int y = 0; y < 20; ++y) top[y] = img[(size_t)y * WW + x];
#pragma unroll
    for (int y = 0; y < 20; ++y) bot[y] = img[(size_t)(492 + y) * WW + x];

    float t1 = 0.f, t2 = 0.f, b1 = 0.f, b2 = 0.f;
#pragma unroll
    for (int y = 0; y < 20; ++y) {
        t1 += top[y]; t2 += top[y] * top[y];
        b1 += bot[y]; b2 += bot[y] * bot[y];
    }
    float i1 = 0.f, i2 = 0.f;
#pragma unroll
    for (int o = 0; o < 8; ++o) {
        i1 += I1p[((size_t)(b * 8 + o)) * 512 + x];
        i2 += I2p[((size_t)(b * 8 + o)) * 512 + x];
    }
    int lane = x & 63, wv = x >> 6;

    // template totals (64 partials -> wave 0)
    if (x < 64) {
        double d1 = tplS1p[x], d2 = tplS2p[x];
        for (int off = 32; off; off >>= 1) {
            d1 += __shfl_down(d1, off);
            d2 += __shfl_down(d2, off);
        }
        if (x == 0) { tS1s = d1; tS2s = d2; }
    }

    // frame total
    double tot = (double)i1 + (double)t1 + (double)b1;
    for (int off = 32; off; off >>= 1) tot += __shfl_down(tot, off);
    if (lane == 0) wrT[wv] = tot;

    // per-u column-window sums (register sliding), block totals + edge cols
    float s1 = i1 + t1, s2 = i2 + t2;
#pragma unroll
    for (int u = 0; u < NS; ++u) {
        if (u) {
            float a = top[u-1], c = bot[u-1];
            s1 += c - a;
            s2 += c * c - a * a;
        }
        double d1 = (double)s1, d2 = (double)s2;
        for (int off = 32; off; off >>= 1) {
            d1 += __shfl_down(d1, off);
            d2 += __shfl_down(d2, off);
        }
        if (lane == 0) { wr1[u][wv] = d1; wr2[u][wv] = d2; }
        if (x < 20)        { e1[u][x]       = s1; e2[u][x]       = s2; }
        else if (x >= 492) { e1[u][x - 472] = s1; e2[u][x - 472] = s2; }
    }
    __syncthreads();
    if (x == 0) {
        double s = 0.0;
        for (int i = 0; i < 8; ++i) s += wrT[i];
        sum1b = s;
    }
    if (x < NS) {
        double a = 0.0, c = 0.0;
        for (int i = 0; i < 8; ++i) { a += wr1[x][i]; c += wr2[x][i]; }
        totals1[x] = a; totals2[x] = c;
    }
    __syncthreads();
    if (x < NS * NS) {
        int u = x / NS, v = x - NS * u;
        double S1 = totals1[u], S2 = totals2[u];
        for (int j = 0; j < v; ++j)  { S1 -= (double)e1[u][j];      S2 -= (double)e2[u][j]; }
        for (int j = v; j < 20; ++j) { S1 -= (double)e1[u][20 + j]; S2 -= (double)e2[u][20 + j]; }
        const double inv = 1.0 / ((double)KWIN * (double)KWIN);
        double m1 = S1 * inv, m2 = S2 * inv;
        double var = m2 - (m1 * m1) * inv + 1e-8;   // reference's formula
        if (var < 0.0) var = 0.0;
        double tv = tS2s - tS1s * tS1s * (1.0 / (double)NPIX) + 1e-8;
        denomS[x] = (float)sqrt(tv * var);
    }
    __syncthreads();

    // RELAXED spin with back-off (no per-poll cache invalidation), then one
    // acquire fence before reading cc8.
    if (t == 0) {
        while (__hip_atomic_load(flag, __ATOMIC_RELAXED,
                                 __HIP_MEMORY_SCOPE_AGENT) < 224)
            __builtin_amdgcn_s_sleep(16);
    }
    __syncthreads();
    __threadfence();                              // acquire side

    if (t < 64) {
        float corr = (float)(sum1b * tS1s * (1.0 / (double)NPIX));
        auto ccAt = [&](int m) -> float {
            int jj = ((m >> 4) * 512) + b * 16 + (m & 15);
            float s = 0.f;
#pragma unroll
            for (int o = 0; o < 8; ++o) s += cc8[(size_t)o * PARTSZ + jj];
            return s;
        };
        float best = -1e30f; int bidx = NS * NS;
        for (int i = t; i < NS * NS; i += 64) {
            float v = fabsf(ccAt(i) - corr) / denomS[i];
            if (v != v) v = 0.f;               // NaN -> 0 (matches reference)
            if (v > best) { best = v; bidx = i; }
        }
        for (int off = 32; off; off >>= 1) {
            float ov = __shfl_down(best, off);
            int   oi = __shfl_down(bidx, off);
            if (ov > best || (ov == best && oi < bidx)) { best = ov; bidx = oi; }
        }
        if (t == 0) {
            int shx = bidx / NS, shy = bidx % NS;
            auto nccAt = [&](int i, int j) -> float {
                i = (i < 0) ? i + NS : i; i = (i > NS - 1) ? NS - 1 : i;  // jnp wrap-then-clamp
                j = (j < 0) ? j + NS : j; j = (j > NS - 1) ? NS - 1 : j;
                float v = fabsf(ccAt(i * NS + j) - corr) / denomS[i * NS + j];
                if (v != v) v = 0.f;
                return v;
            };
            float lc  = logf(nccAt(shx, shy));
            float lxm = logf(nccAt(shx - 1, shy));
            float lxp = logf(nccAt(shx + 1, shy));
            float lym = logf(nccAt(shx, shy - 1));
            float lyp = logf(nccAt(shx, shy + 1));
            float shxn = -(float)(shx - 10) - (lxm - lxp) / (2.f * lxm - 4.f * lc + 2.f * lxp);
            float shyn = -(float)(shy - 10) - (lym - lyp) / (2.f * lym - 4.f * lc + 2.f * lyp);
            shifts[b]      = shxn;   // dy
            shifts[32 + b] = shyn;   // dx
        }
    }
}

// ---------------- Kernel B: bilinear warp + transposed write ----------------
__device__ __forceinline__ float samp(const float* __restrict__ img, int y, int x) {
    bool valid = (y >= 0) & (y < HH) & (x >= 0) & (x < WW);
    int yc = min(max(y, 0), HH - 1), xc = min(max(x, 0), WW - 1);
    float v = img[(size_t)yc * WW + xc];
    return valid ? v : 0.f;
}

__global__ __launch_bounds__(256) void warp_kernel(
    const float* __restrict__ fr, const float* __restrict__ shifts,
    float* __restrict__ out)
{
    int b  = blockIdx.z;
    int h0 = blockIdx.y * 32;
    int w0 = blockIdx.x * 32;
    float dy = shifts[b], dx = shifts[32 + b];
    const float* img = fr + (size_t)b * NPIX;
    __shared__ float tile[32][33];
    int tx = threadIdx.x & 31;
    int tz = threadIdx.x >> 5;
#pragma unroll
    for (int s = 0; s < 4; ++s) {
        int h = h0 + tz + 8 * s;
        int w = w0 + tx;
        float yq = (float)h - dy;
        float xq = (float)w - dx;
        float y0f = floorf(yq), x0f = floorf(xq);
        float wy = yq - y0f, wx = xq - x0f;
        int y0 = (int)y0f, x0 = (int)x0f;
        float v00 = samp(img, y0,     x0);
        float v01 = samp(img, y0,     x0 + 1);
        float v10 = samp(img, y0 + 1, x0);
        float v11 = samp(img, y0 + 1, x0 + 1);
        float val = v00 * (1.f - wy) * (1.f - wx) + v01 * (1.f - wy) * wx
                  + v10 * wy * (1.f - wx)         + v11 * wy * wx;
        tile[tz + 8 * s][tx] = val;
    }
    __syncthreads();
#pragma unroll
    for (int s = 0; s < 4; ++s) {
        int hh = tx;
        int ww = tz + 8 * s;
        out[(size_t)b * NPIX + (size_t)(w0 + ww) * HH + (h0 + hh)] = tile[hh][ww];
    }
}

// ---------------- launch ----------------------------------------------------
extern "C" void kernel_launch(void* const* d_in, const int* in_sizes, int n_in,
                              void* d_out, int out_size, void* d_ws, size_t ws_size,
                              hipStream_t stream) {
    const float* fr  = (const float*)d_in[0];   // (1,32,512,512,1) flat
    const float* tpl = (const float*)d_in[1];   // (512,512)
    float* out = (float*)d_out;
    char* ws = (char*)d_ws;

    // ws layout (~23 MB), every buffer fully rewritten each launch -> no memset
    unsigned short* tplb = (unsigned short*)(ws + 0);        // 1.11 MB (2 copies)
    float*  I1p    = (float*) (ws + 2097152);                // 512 KB (256*512 f)
    float*  I2p    = (float*) (ws + 2621440);                // 512 KB
    double* tplS1p = (double*)(ws + 3145728);                // 512 B
    double* tplS2p = (double*)(ws + 3146240);                // 512 B
    float*  shifts = (float*) (ws + 3146752);                // 256 B
    int*    flag   = (int*)   (ws + 3147264);                // 4 B
    float*  cc8    = (float*) (ws + 4194304);                // 458 KB
    float*  part   = (float*) (ws + 8388608);                // 14.68 MB (256 chunks)

    prep     <<<448, 512, 0, stream>>>(fr, tpl, tplb, I1p, I2p, tplS1p, tplS2p, flag);
    corr_mfma<<<256, 896, 0, stream>>>(fr, tplb, part);
    reduce_am<<<256, 512, 0, stream>>>(part, cc8, fr, I1p, I2p, tplS1p, tplS2p, flag, shifts);
    warp_kernel<<<dim3(16, 16, 32), 256, 0, stream>>>(fr, shifts, out);
}

// Round 10
// 150.805 us; speedup vs baseline: 2.0436x; 1.1239x over previous
//
#include <hip/hip_runtime.h>
#include <math.h>

#define HH 512
#define WW 512
#define NPIX (HH*WW)
#define NB 32
#define NS 21           // 2*MS+1 shifts per axis
#define KWIN 492        // window size (H - 2*10)
#define NKB 256         // split-K chunks (1024 k each)
#define MT28 28         // m-tiles (448 = 28*16, M=441 padded)
#define PARTSZ (MT28*32*16)   // 14336 floats per k-chunk
#define TPLB_COPY 278528      // 512*544 shorts per parity copy

typedef __attribute__((ext_vector_type(8))) short short8;
typedef __attribute__((ext_vector_type(4))) float floatx4;

__device__ __forceinline__ unsigned short f2bf(float f) {
    unsigned u = __float_as_uint(f);
    unsigned r = (u + 0x7fffu + ((u >> 16) & 1u)) >> 16;
    return (unsigned short)r;
}

// 16B fragment load from a 4B-aligned address (tplb cols are even, not x8).
__device__ __forceinline__ short8 loadA(const unsigned short* p) {
    union { short8 v; unsigned u[4]; } r;
    const unsigned* q = (const unsigned*)p;
    r.u[0] = q[0]; r.u[1] = q[1]; r.u[2] = q[2]; r.u[3] = q[3];
    return r.v;
}

// ---------------- prep: interior col partial sums (256 blk), template partial
//   sums (64 blk), padded bf16 template (128 blk). No atomics, no flag.
__global__ __launch_bounds__(512) void prep(
    const float* __restrict__ fr, const float* __restrict__ tpl,
    unsigned short* __restrict__ tplb,
    float* __restrict__ I1p, float* __restrict__ I2p,
    double* __restrict__ tplS1p, double* __restrict__ tplS2p)
{
    int blk = blockIdx.x;
    int t   = threadIdx.x;

    if (blk < 256) {
        // interior column partial sums: (frame b, row-oct) -> I1p/I2p
        int b = blk >> 3, oct = blk & 7;              // b in [0,32)
        const float* img = fr + (size_t)b * NPIX;
        int x = t;
        float s1 = 0.f, s2 = 0.f;
        int y0 = 20 + 59 * oct;                       // rows 20..491 = 8*59
        for (int y = y0; y < y0 + 59; ++y) {
            float v = img[(size_t)y * WW + x];
            s1 += v; s2 += v * v;
        }
        I1p[(size_t)blk * 512 + x] = s1;
        I2p[(size_t)blk * 512 + x] = s2;
    } else if (blk < 320) {
        // template partial sums: 64 jobs of 8 rows
        __shared__ double jb1[8], jb2[8];
        int tj = blk - 256;
        const float* trow = tpl + (size_t)tj * 8 * WW;
        float s1 = 0.f, s2 = 0.f;
        int x = t;
        for (int y = 0; y < 8; ++y) {
            float v = trow[(size_t)y * WW + x];
            s1 += v; s2 += v * v;
        }
        double d1 = (double)s1, d2 = (double)s2;
        for (int off = 32; off; off >>= 1) {
            d1 += __shfl_down(d1, off);
            d2 += __shfl_down(d2, off);
        }
        int lane = t & 63, wv = t >> 6;
        if (lane == 0) { jb1[wv] = d1; jb2[wv] = d2; }
        __syncthreads();
        if (t == 0) {
            double a = 0.0, c = 0.0;
            for (int i = 0; i < 8; ++i) { a += jb1[i]; c += jb2[i]; }
            tplS1p[tj] = a; tplS2p[tj] = c;
        }
    } else {
        // padded bf16 template: copyP[sy][c] = bf16(tpl[sy][(c-16-P) mod 512])
        int sy0 = (blk - 320) * 4;                    // 128 blocks x 4 rows
#pragma unroll
        for (int rr = 0; rr < 4; ++rr) {
            int sy = sy0 + rr;
            const float* srow = tpl + (size_t)sy * WW;
#pragma unroll
            for (int P = 0; P < 2; ++P) {
                for (int c = t; c < 544; c += 512) {
                    int sx = (c + 496 - P) & 511;     // (c-16-P) mod 512
                    tplb[(size_t)P * TPLB_COPY + (size_t)sy * 544 + c] = f2bf(srow[sx]);
                }
            }
        }
    }
}

// ---------------- Kernel C: implicit-GEMM correlation via MFMA --------------
// NKB=256 chunks of 1024 k (= 2 image rows of all 32 frames). One block per
// chunk: 896 thr = 14 waves x 2 m-tiles. Two 512-k sub-chunks staged into LDS
// sequentially, ACCUMULATING in registers. A fragments from the 1.1 MB padded
// template (L2-hot): tplb[P=dv&1][(row+522-du)&511][x - dv + 26 + P].
__global__ __launch_bounds__(896) void corr_mfma(
    const float* __restrict__ fr,
    const unsigned short* __restrict__ tplb,
    float* __restrict__ part)
{
    __shared__ unsigned short Bs[16384];   // [k8][frame][8] : 512k x 32fr, 32 KB

    const int t   = threadIdx.x;
    const int l   = t & 63;
    const int wid = t >> 6;               // wave 0..13 = tile-pair
    const int idx = blockIdx.x;           // 0..255
    const int kb  = ((idx & 7) << 5) | (idx >> 3);   // XCD swizzle (32/XCD)
    const int kg  = l >> 4;               // k-group 0..3
    const int ln  = l & 15;

    // m-geometry (sub-chunk independent)
    int du0, dv0, du1, dv1;
    {
        int m_g = 32 * wid + ln;           // mt = 0
        du0 = (m_g * 1561) >> 15;          // m_g/21 exact for m_g<=447
        dv0 = m_g - 21 * du0;
        if (m_g >= 441) { du0 = 0; dv0 = 0; }   // pad rows: loaded, never used
        m_g = 32 * wid + 16 + ln;          // mt = 1
        du1 = (m_g * 1561) >> 15;
        dv1 = m_g - 21 * du1;
        if (m_g >= 441) { du1 = 0; dv1 = 0; }
    }
    const int P0 = dv0 & 1, P1 = dv1 & 1;
    const int col0 = 8 * kg - dv0 + 26 + P0;
    const int col1 = 8 * kg - dv1 + 26 + P1;

    const unsigned short* lB = Bs + kg * 256 + ln * 8;

    floatx4 acc00 = {}, acc01 = {}, acc10 = {}, acc11 = {};

#pragma unroll 1
    for (int c = 0; c < 2; ++c) {
        const int row = 2 * kb + c;          // template/frame image row
        const int k0  = row << 9;            // global k base of this sub-chunk
        if (c) __syncthreads();              // WAR on Bs
        // stage: fr slice -> bf16 interleave in LDS (coalesced 16B loads)
        for (int i = t; i < 4096; i += 896) {
            int frame = i >> 7, q = i & 127;
            float4 v = *(const float4*)(fr + (size_t)frame * NPIX + k0 + 4 * q);
            int k8 = q >> 1, j4 = (q & 1) * 4;
            ushort4 o;
            o.x = f2bf(v.x); o.y = f2bf(v.y); o.z = f2bf(v.z); o.w = f2bf(v.w);
            *(ushort4*)&Bs[(k8 * 32 + frame) * 8 + j4] = o;
        }
        __syncthreads();

        const unsigned short* pA0 = tplb + (size_t)P0 * TPLB_COPY
            + (size_t)((row + 522 - du0) & 511) * 544 + col0;
        const unsigned short* pA1 = tplb + (size_t)P1 * TPLB_COPY
            + (size_t)((row + 522 - du1) & 511) * 544 + col1;

#pragma unroll
        for (int ks = 0; ks < 16; ++ks) {    // 16 steps x 32 k = 512
            short8 A0 = loadA(pA0);
            short8 A1 = loadA(pA1);
            short8 B0 = *(const short8*)(lB + ks * 1024);         // frames 0..15
            short8 B1 = *(const short8*)(lB + ks * 1024 + 128);   // frames 16..31
            acc00 = __builtin_amdgcn_mfma_f32_16x16x32_bf16(A0, B0, acc00, 0, 0, 0);
            acc01 = __builtin_amdgcn_mfma_f32_16x16x32_bf16(A0, B1, acc01, 0, 0, 0);
            acc10 = __builtin_amdgcn_mfma_f32_16x16x32_bf16(A1, B0, acc10, 0, 0, 0);
            acc11 = __builtin_amdgcn_mfma_f32_16x16x32_bf16(A1, B1, acc11, 0, 0, 0);
            pA0 += 32; pA1 += 32;
        }
    }

    // dense partial stores: part[((kb*28 + mtile)*32 + n)*16 + mr], mr=4kg+r
    {
        size_t base = ((size_t)kb * MT28 + 2 * wid) * 32;
        floatx4* p;
        p = (floatx4*)(part + (base + ln)      * 16 + 4 * kg); *p = acc00;
        p = (floatx4*)(part + (base + 16 + ln) * 16 + 4 * kg); *p = acc01;
        p = (floatx4*)(part + (base + 32 + ln) * 16 + 4 * kg); *p = acc10;
        p = (floatx4*)(part + (base + 48 + ln) * 16 + 4 * kg); *p = acc11;
    }
}

// ---------------- reduce: part (256 k-chunks) -> cc8 (8 oct partials) -------
// 224 blocks x 512. Disjoint writes, no atomics. Kernel boundary provides
// cross-XCD visibility to stage2_am (no flag/spin — R8's 35us tail removed).
__global__ __launch_bounds__(512) void reduce_k(
    const float* __restrict__ part, float* __restrict__ cc8)
{
    int blk = blockIdx.x;
    int oct = blk / 28;                      // 0..7 (32 kb-chunks each)
    int j   = (blk % 28) * 512 + threadIdx.x;
    const float* p = part + (size_t)(oct * 32) * PARTSZ + j;
    float s = 0.f;
#pragma unroll 8
    for (int i = 0; i < 32; ++i)
        s += p[(size_t)i * PARTSZ];
    cc8[(size_t)oct * PARTSZ + j] = s;
}

// ---------------- stage2 + argmax + subpixel: 32 blocks (one per frame) -----
__global__ __launch_bounds__(512) void stage2_am(
    const float* __restrict__ cc8, const float* __restrict__ fr,
    const float* __restrict__ I1p, const float* __restrict__ I2p,
    const double* __restrict__ tplS1p, const double* __restrict__ tplS2p,
    float* __restrict__ shifts)
{
    __shared__ double wr1[NS][8], wr2[NS][8], wrT[8];
    __shared__ float  e1[NS][40], e2[NS][40];
    __shared__ double totals1[NS], totals2[NS];
    __shared__ float  denomS[NS * NS];
    __shared__ double tS1s, tS2s, sum1b;

    int b = blockIdx.x;
    int x = threadIdx.x;
    const float* img = fr + (size_t)b * NPIX;
    float top[20], bot[20];
#pragma unroll
    for (int y = 0; y < 20; ++y) top[y] = img[(size_t)y * WW + x];
#pragma unroll
    for (int y = 0; y < 20; ++y) bot[y] = img[(size_t)(492 + y) * WW + x];

    float t1 = 0.f, t2 = 0.f, b1 = 0.f, b2 = 0.f;
#pragma unroll
    for (int y = 0; y < 20; ++y) {
        t1 += top[y]; t2 += top[y] * top[y];
        b1 += bot[y]; b2 += bot[y] * bot[y];
    }
    float i1 = 0.f, i2 = 0.f;
#pragma unroll
    for (int o = 0; o < 8; ++o) {
        i1 += I1p[((size_t)(b * 8 + o)) * 512 + x];
        i2 += I2p[((size_t)(b * 8 + o)) * 512 + x];
    }
    int lane = x & 63, wv = x >> 6;

    // template totals (64 partials -> wave 0)
    if (x < 64) {
        double d1 = tplS1p[x], d2 = tplS2p[x];
        for (int off = 32; off; off >>= 1) {
            d1 += __shfl_down(d1, off);
            d2 += __shfl_down(d2, off);
        }
        if (x == 0) { tS1s = d1; tS2s = d2; }
    }

    // frame total
    double tot = (double)i1 + (double)t1 + (double)b1;
    for (int off = 32; off; off >>= 1) tot += __shfl_down(tot, off);
    if (lane == 0) wrT[wv] = tot;

    // per-u column-window sums (register sliding), block totals + edge cols
    float s1 = i1 + t1, s2 = i2 + t2;
#pragma unroll
    for (int u = 0; u < NS; ++u) {
        if (u) {
            float a = top[u-1], c = bot[u-1];
            s1 += c - a;
            s2 += c * c - a * a;
        }
        double d1 = (double)s1, d2 = (double)s2;
        for (int off = 32; off; off >>= 1) {
            d1 += __shfl_down(d1, off);
            d2 += __shfl_down(d2, off);
        }
        if (lane == 0) { wr1[u][wv] = d1; wr2[u][wv] = d2; }
        if (x < 20)        { e1[u][x]       = s1; e2[u][x]       = s2; }
        else if (x >= 492) { e1[u][x - 472] = s1; e2[u][x - 472] = s2; }
    }
    __syncthreads();
    if (x == 0) {
        double s = 0.0;
        for (int i = 0; i < 8; ++i) s += wrT[i];
        sum1b = s;
    }
    if (x < NS) {
        double a = 0.0, c = 0.0;
        for (int i = 0; i < 8; ++i) { a += wr1[x][i]; c += wr2[x][i]; }
        totals1[x] = a; totals2[x] = c;
    }
    __syncthreads();
    if (x < NS * NS) {
        int u = x / NS, v = x - NS * u;
        double S1 = totals1[u], S2 = totals2[u];
        for (int j = 0; j < v; ++j)  { S1 -= (double)e1[u][j];      S2 -= (double)e2[u][j]; }
        for (int j = v; j < 20; ++j) { S1 -= (double)e1[u][20 + j]; S2 -= (double)e2[u][20 + j]; }
        const double inv = 1.0 / ((double)KWIN * (double)KWIN);
        double m1 = S1 * inv, m2 = S2 * inv;
        double var = m2 - (m1 * m1) * inv + 1e-8;   // reference's formula
        if (var < 0.0) var = 0.0;
        double tv = tS2s - tS1s * tS1s * (1.0 / (double)NPIX) + 1e-8;
        denomS[x] = (float)sqrt(tv * var);
    }
    __syncthreads();

    if (x < 64) {
        float corr = (float)(sum1b * tS1s * (1.0 / (double)NPIX));
        auto ccAt = [&](int m) -> float {
            int jj = ((m >> 4) * 512) + b * 16 + (m & 15);
            float s = 0.f;
#pragma unroll
            for (int o = 0; o < 8; ++o) s += cc8[(size_t)o * PARTSZ + jj];
            return s;
        };
        float best = -1e30f; int bidx = NS * NS;
        for (int i = x; i < NS * NS; i += 64) {
            float v = fabsf(ccAt(i) - corr) / denomS[i];
            if (v != v) v = 0.f;               // NaN -> 0 (matches reference)
            if (v > best) { best = v; bidx = i; }
        }
        for (int off = 32; off; off >>= 1) {
            float ov = __shfl_down(best, off);
            int   oi = __shfl_down(bidx, off);
            if (ov > best || (ov == best && oi < bidx)) { best = ov; bidx = oi; }
        }
        if (x == 0) {
            int shx = bidx / NS, shy = bidx % NS;
            auto nccAt = [&](int i, int j) -> float {
                i = (i < 0) ? i + NS : i; i = (i > NS - 1) ? NS - 1 : i;  // jnp wrap-then-clamp
                j = (j < 0) ? j + NS : j; j = (j > NS - 1) ? NS - 1 : j;
                float v = fabsf(ccAt(i * NS + j) - corr) / denomS[i * NS + j];
                if (v != v) v = 0.f;
                return v;
            };
            float lc  = logf(nccAt(shx, shy));
            float lxm = logf(nccAt(shx - 1, shy));
            float lxp = logf(nccAt(shx + 1, shy));
            float lym = logf(nccAt(shx, shy - 1));
            float lyp = logf(nccAt(shx, shy + 1));
            float shxn = -(float)(shx - 10) - (lxm - lxp) / (2.f * lxm - 4.f * lc + 2.f * lxp);
            float shyn = -(float)(shy - 10) - (lym - lyp) / (2.f * lym - 4.f * lc + 2.f * lyp);
            shifts[b]      = shxn;   // dy
            shifts[32 + b] = shyn;   // dx
        }
    }
}

// ---------------- Kernel B: bilinear warp + transposed write ----------------
__device__ __forceinline__ float samp(const float* __restrict__ img, int y, int x) {
    bool valid = (y >= 0) & (y < HH) & (x >= 0) & (x < WW);
    int yc = min(max(y, 0), HH - 1), xc = min(max(x, 0), WW - 1);
    float v = img[(size_t)yc * WW + xc];
    return valid ? v : 0.f;
}

__global__ __launch_bounds__(256) void warp_kernel(
    const float* __restrict__ fr, const float* __restrict__ shifts,
    float* __restrict__ out)
{
    int b  = blockIdx.z;
    int h0 = blockIdx.y * 32;
    int w0 = blockIdx.x * 32;
    float dy = shifts[b], dx = shifts[32 + b];
    const float* img = fr + (size_t)b * NPIX;
    __shared__ float tile[32][33];
    int tx = threadIdx.x & 31;
    int tz = threadIdx.x >> 5;
#pragma unroll
    for (int s = 0; s < 4; ++s) {
        int h = h0 + tz + 8 * s;
        int w = w0 + tx;
        float yq = (float)h - dy;
        float xq = (float)w - dx;
        float y0f = floorf(yq), x0f = floorf(xq);
        float wy = yq - y0f, wx = xq - x0f;
        int y0 = (int)y0f, x0 = (int)x0f;
        float v00 = samp(img, y0,     x0);
        float v01 = samp(img, y0,     x0 + 1);
        float v10 = samp(img, y0 + 1, x0);
        float v11 = samp(img, y0 + 1, x0 + 1);
        float val = v00 * (1.f - wy) * (1.f - wx) + v01 * (1.f - wy) * wx
                  + v10 * wy * (1.f - wx)         + v11 * wy * wx;
        tile[tz + 8 * s][tx] = val;
    }
    __syncthreads();
#pragma unroll
    for (int s = 0; s < 4; ++s) {
        int hh = tx;
        int ww = tz + 8 * s;
        out[(size_t)b * NPIX + (size_t)(w0 + ww) * HH + (h0 + hh)] = tile[hh][ww];
    }
}

// ---------------- launch ----------------------------------------------------
extern "C" void kernel_launch(void* const* d_in, const int* in_sizes, int n_in,
                              void* d_out, int out_size, void* d_ws, size_t ws_size,
                              hipStream_t stream) {
    const float* fr  = (const float*)d_in[0];   // (1,32,512,512,1) flat
    const float* tpl = (const float*)d_in[1];   // (512,512)
    float* out = (float*)d_out;
    char* ws = (char*)d_ws;

    // ws layout (~23 MB), every buffer fully rewritten each launch -> no memset
    unsigned short* tplb = (unsigned short*)(ws + 0);        // 1.11 MB (2 copies)
    float*  I1p    = (float*) (ws + 2097152);                // 512 KB (256*512 f)
    float*  I2p    = (float*) (ws + 2621440);                // 512 KB
    double* tplS1p = (double*)(ws + 3145728);                // 512 B
    double* tplS2p = (double*)(ws + 3146240);                // 512 B
    float*  shifts = (float*) (ws + 3146752);                // 256 B
    float*  cc8    = (float*) (ws + 4194304);                // 458 KB
    float*  part   = (float*) (ws + 8388608);                // 14.68 MB (256 chunks)

    prep      <<<448, 512, 0, stream>>>(fr, tpl, tplb, I1p, I2p, tplS1p, tplS2p);
    corr_mfma <<<256, 896, 0, stream>>>(fr, tplb, part);
    reduce_k  <<<224, 512, 0, stream>>>(part, cc8);
    stage2_am <<<32, 512, 0, stream>>>(cc8, fr, I1p, I2p, tplS1p, tplS2p, shifts);
    warp_kernel<<<dim3(16, 16, 32), 256, 0, stream>>>(fr, shifts, out);
}